// Round 4
// baseline (7587.107 us; speedup 1.0000x reference)
//
#include <hip/hip_runtime.h>
#include <hip/hip_bf16.h>
#include <math.h>

#define Bn 128
#define Sn 128
#define Tn 8
#define En 300
#define Hn 512
#define Gn 2048
#define C2n 1024
#define NCONV 50
#define CH 16
#define NCH 8

// ---------------- workspace layout (float-unit offsets, total ~77 MB) ----------------
#define OFF_X1C   0L          // bf16 2*128*16*2048 = 8,388,608 elems
#define OFF_X2    4194304L    // bf16 2*128*8*2048  = 4,194,304 elems
#define OFF_FEAT  6291456L    // bf16 128*128*300   = 4,915,200 elems
#define OFF_ASP   8749056L    // bf16 128*8*300     =   307,200 elems
#define OFF_V     8902656L    // bf16 128*128*1024  = 16,777,216 elems
#define OFF_E     17291264L   // bf16 128*8*1024    =  1,048,576 elems
#define OFF_F2    17815552L   // bf16 128*8*1024    =  1,048,576 elems
#define OFF_STATE 18339840L   // f32 786,432 (12 x 65536)
#define OFF_LENF  19126272L
#define OFF_LENA  19126400L
#define OFF_RMF1  19126528L   // 16384 ints
#define OFF_RMB1  19142912L   // 16384 ints
#define OFF_RM2   19159296L   // 1024 ints
#define OFF_WPOS  19160320L   // 16384 f32
#define OFF_ZMAX  19176704L   // 6400 f32
// end = 19,183,104 floats = 76.7 MB
#define OFF_MO    0L          // bf16 16,777,216 elems; reuses X1C/X2/FEAT/ASP (dead after LSTMs)

typedef unsigned short ushort_t;

__device__ __forceinline__ float sigm_(float x){ return 1.f/(1.f + __expf(-x)); }
__device__ __forceinline__ float tanh_(float x){ return 2.f/(1.f + __expf(-2.f*x)) - 1.f; }
__device__ __forceinline__ float bfu2f(ushort_t u){ return __uint_as_float(((unsigned int)u) << 16); }
__device__ __forceinline__ ushort_t f2bfu(float f){
    __hip_bfloat16 h = __float2bfloat16(f);
    return *reinterpret_cast<ushort_t*>(&h);
}

// ---------------- zero state ----------------
__global__ void zero_kernel(float* __restrict__ p, long n){
    long i = (long)blockIdx.x*256 + threadIdx.x;
    if (i < n) p[i] = 0.f;
}

// ---------------- prep: lengths, chunk-ordered gather maps, position weights ----------------
__global__ __launch_bounds__(128) void prep_kernel(
    const int* __restrict__ raw_text, const int* __restrict__ target,
    const int* __restrict__ span,
    int* __restrict__ lenf, int* __restrict__ lena,
    int* __restrict__ rmF1, int* __restrict__ rmB1, int* __restrict__ rm2,
    float* __restrict__ wpos)
{
    int b = blockIdx.x, tid = threadIdx.x;
    __shared__ int sh[128];
    sh[tid] = (raw_text[b*Sn + tid] != 0) ? 1 : 0;
    __syncthreads();
    for (int off = 64; off > 0; off >>= 1){
        if (tid < off) sh[tid] += sh[tid + off];
        __syncthreads();
    }
    __shared__ int lfs, las;
    if (tid == 0){
        lfs = sh[0]; lenf[b] = lfs;
        int c = 0;
        for (int tt = 0; tt < Tn; tt++) c += (target[b*Tn + tt] != 0) ? 1 : 0;
        las = c; lena[b] = c;
    }
    __syncthreads();
    int Lf = lfs, La = las;
    int t = tid;
    int c = t >> 4, tt = t & 15;      // chunk, in-chunk index (CH=16)
    int rev = (t < Lf) ? (Lf - 1 - t) : t;
    rmF1[(c*Bn + b)*CH + tt] = b*Sn + t;
    rmB1[(c*Bn + b)*CH + tt] = b*Sn + rev;
    if (t < Tn) rm2[b*Tn + t] = b*Tn + ((t < La) ? (La - 1 - t) : t);
    float p0 = (float)span[b*2 + 0], p1 = (float)span[b*2 + 1];
    float j = (float)t;
    wpos[b*Sn + t] = (j < p1) ? (1.0f - (p1 - j)/40.0f) : (1.0f - (j - p0)/40.0f);
}

// ---------------- embedding gather -> bf16 ----------------
__global__ void embed_kernel(const int* __restrict__ ids, const float* __restrict__ embW,
                             ushort_t* __restrict__ out, long nelem)
{
    long i = (long)blockIdx.x*256 + threadIdx.x;
    if (i >= nelem) return;
    long r = i / En; int c = (int)(i - r*En);
    out[i] = f2bfu(embW[(long)ids[r]*En + c]);
}

// ---------------- GEMM: C[m,n] = bias[n] + sum_k A[rowmap(m),k]*W[n,k]; A bf16, W f32, C bf16 ----
__global__ __launch_bounds__(256) void gemm_bf16(
    const ushort_t* __restrict__ A, int lda, const int* __restrict__ rowmap,
    const float* __restrict__ W, int ldw, const float* __restrict__ bias,
    ushort_t* __restrict__ C, int ldc, int M, int N, int K)
{
    __shared__ float As[16][64];
    __shared__ float Ws[16][64];
    int tid = threadIdx.x;
    int m0 = blockIdx.y*64, n0 = blockIdx.x*64;
    int lm = tid >> 2;           // 0..63
    int lk = (tid & 3) * 4;      // 0,4,8,12
    int ty = tid >> 4, tx = tid & 15;

    float acc[4][4];
    #pragma unroll
    for (int i = 0; i < 4; i++)
        #pragma unroll
        for (int j = 0; j < 4; j++) acc[i][j] = 0.f;

    int srcA = m0 + lm;
    if (rowmap) srcA = rowmap[srcA];
    const ushort_t* Arow = A + (long)srcA*lda;
    int nW = n0 + lm;
    const float* Wrow = (nW < N) ? (W + (long)nW*ldw) : nullptr;

    for (int k0 = 0; k0 < K; k0 += 16){
        float a0=0.f,a1=0.f,a2=0.f,a3=0.f, w0=0.f,w1=0.f,w2=0.f,w3=0.f;
        if (k0 + 16 <= K){
            ushort4 t4 = *(const ushort4*)(Arow + k0 + lk);
            a0=bfu2f(t4.x); a1=bfu2f(t4.y); a2=bfu2f(t4.z); a3=bfu2f(t4.w);
            if (Wrow){ float4 f4 = *(const float4*)(Wrow + k0 + lk); w0=f4.x;w1=f4.y;w2=f4.z;w3=f4.w; }
        } else {
            int kb = k0 + lk;
            if (kb   < K) a0 = bfu2f(Arow[kb]);
            if (kb+1 < K) a1 = bfu2f(Arow[kb+1]);
            if (kb+2 < K) a2 = bfu2f(Arow[kb+2]);
            if (kb+3 < K) a3 = bfu2f(Arow[kb+3]);
            if (Wrow){
                if (kb   < K) w0 = Wrow[kb];
                if (kb+1 < K) w1 = Wrow[kb+1];
                if (kb+2 < K) w2 = Wrow[kb+2];
                if (kb+3 < K) w3 = Wrow[kb+3];
            }
        }
        __syncthreads();
        As[lk+0][lm]=a0; As[lk+1][lm]=a1; As[lk+2][lm]=a2; As[lk+3][lm]=a3;
        Ws[lk+0][lm]=w0; Ws[lk+1][lm]=w1; Ws[lk+2][lm]=w2; Ws[lk+3][lm]=w3;
        __syncthreads();
        #pragma unroll
        for (int kk = 0; kk < 16; kk++){
            float4 av = *(const float4*)&As[kk][ty*4];
            float4 wv = *(const float4*)&Ws[kk][tx*4];
            acc[0][0] += av.x*wv.x; acc[0][1] += av.x*wv.y; acc[0][2] += av.x*wv.z; acc[0][3] += av.x*wv.w;
            acc[1][0] += av.y*wv.x; acc[1][1] += av.y*wv.y; acc[1][2] += av.y*wv.z; acc[1][3] += av.y*wv.w;
            acc[2][0] += av.z*wv.x; acc[2][1] += av.z*wv.y; acc[2][2] += av.z*wv.z; acc[2][3] += av.z*wv.w;
            acc[3][0] += av.w*wv.x; acc[3][1] += av.w*wv.y; acc[3][2] += av.w*wv.z; acc[3][3] += av.w*wv.w;
        }
    }
    #pragma unroll
    for (int i = 0; i < 4; i++){
        int m = m0 + ty*4 + i; if (m >= M) continue;
        #pragma unroll
        for (int j = 0; j < 4; j++){
            int n = n0 + tx*4 + j; if (n >= N) continue;
            float v = acc[i][j];
            if (bias) v += bias[n];
            C[(long)m*ldc + n] = f2bfu(v);
        }
    }
}

// ---------------- fused LSTM step ----------------
__global__ __launch_bounds__(256) void lstm_step_kernel(
    const ushort_t* __restrict__ Xf, const ushort_t* __restrict__ Xb,
    const float* __restrict__ Whf, const float* __restrict__ Whb,
    const float* __restrict__ hpf, const float* __restrict__ hpb,
    float* __restrict__ hnf, float* __restrict__ hnb,
    float* __restrict__ cfp, float* __restrict__ cbp,
    ushort_t* __restrict__ out, const int* __restrict__ lens,
    int t, int tloc, int Pout, int CHin)
{
    int dir = blockIdx.z;
    const ushort_t* X = dir ? Xb  : Xf;
    const float* Wh = dir ? Whb : Whf;
    const float* hp = dir ? hpb : hpf;
    float* hn = dir ? hnb : hnf;
    float* cc = dir ? cbp : cfp;

    int j0 = blockIdx.x * 32;
    int b0 = blockIdx.y * 32;
    int tid = threadIdx.x;
    int tx = tid & 15, ty = tid >> 4;

    __shared__ float Hs[16][32];
    __shared__ float Ws[16][128];

    float acc[4][2][2];
    #pragma unroll
    for (int g = 0; g < 4; g++){ acc[g][0][0]=0.f; acc[g][0][1]=0.f; acc[g][1][0]=0.f; acc[g][1][1]=0.f; }

    int hb = tid >> 3;
    int hk = (tid & 7) * 2;
    int wr = tid >> 1;
    int wg = wr >> 5;
    int wj = wr & 31;
    int wq = (tid & 1) * 8;
    const float* WhRow = Wh + (long)(wg*Hn + j0 + wj)*Hn;
    const float* hpRow = hp + (long)(b0 + hb)*Hn;

    for (int k0 = 0; k0 < Hn; k0 += 16){
        float2 hv = *(const float2*)(hpRow + k0 + hk);
        float4 wa = *(const float4*)(WhRow + k0 + wq);
        float4 wb = *(const float4*)(WhRow + k0 + wq + 4);
        __syncthreads();
        Hs[hk][hb] = hv.x; Hs[hk+1][hb] = hv.y;
        Ws[wq+0][wg*32+wj] = wa.x; Ws[wq+1][wg*32+wj] = wa.y;
        Ws[wq+2][wg*32+wj] = wa.z; Ws[wq+3][wg*32+wj] = wa.w;
        Ws[wq+4][wg*32+wj] = wb.x; Ws[wq+5][wg*32+wj] = wb.y;
        Ws[wq+6][wg*32+wj] = wb.z; Ws[wq+7][wg*32+wj] = wb.w;
        __syncthreads();
        #pragma unroll
        for (int kk = 0; kk < 16; kk++){
            float2 h2 = *(const float2*)&Hs[kk][ty*2];
            #pragma unroll
            for (int g = 0; g < 4; g++){
                float2 w2 = *(const float2*)&Ws[kk][g*32 + tx*2];
                acc[g][0][0] += h2.x*w2.x; acc[g][0][1] += h2.x*w2.y;
                acc[g][1][0] += h2.y*w2.x; acc[g][1][1] += h2.y*w2.y;
            }
        }
    }

    #pragma unroll
    for (int bb = 0; bb < 2; bb++){
        int b = b0 + ty*2 + bb;
        int len = lens[b];
        long xoff = ((long)b*CHin + tloc)*Gn;
        #pragma unroll
        for (int jj = 0; jj < 2; jj++){
            int j = j0 + tx*2 + jj;
            float gi = acc[0][bb][jj] + bfu2f(X[xoff + j]);
            float gf = acc[1][bb][jj] + bfu2f(X[xoff + Hn + j]);
            float gg = acc[2][bb][jj] + bfu2f(X[xoff + 2*Hn + j]);
            float go = acc[3][bb][jj] + bfu2f(X[xoff + 3*Hn + j]);
            float si = sigm_(gi), sf = sigm_(gf), tg = tanh_(gg), so = sigm_(go);
            int ci = b*Hn + j;
            float cn = sf*cc[ci] + si*tg;
            cc[ci] = cn;
            float hv = so * tanh_(cn);
            hn[ci] = hv;
            int pos = dir ? ((t < len) ? (len - 1 - t) : t) : t;
            float val = (t < len) ? hv : 0.f;
            out[((long)b*Pout + pos)*C2n + dir*Hn + j] = f2bfu(val);
        }
    }
}

// ---------------- fused attention + fc1(mid half via F) + residual + pos-weight ----------------
// per (b,s): scores_t = v[b,s,:].e[b,t,:] ; a = softmax_t ; vnew = (relu(mo + sum_t a_t F2[b,t,:] + b1) + v)*w
__global__ __launch_bounds__(256) void attn2_kernel(
    ushort_t* __restrict__ v, const ushort_t* __restrict__ e,
    const ushort_t* __restrict__ F2, const ushort_t* __restrict__ mo,
    const float* __restrict__ fc1_b, const float* __restrict__ wpos)
{
    int s = blockIdx.x, b = blockIdx.y;
    ushort_t* vrow = v + ((long)b*Sn + s)*C2n;
    const ushort_t* eb = e + (long)b*Tn*C2n;
    const ushort_t* Fb = F2 + (long)b*Tn*C2n;
    const ushort_t* morow = mo + ((long)b*Sn + s)*C2n;
    int c0 = threadIdx.x * 4;

    ushort4 vv4 = *(const ushort4*)(vrow + c0);
    float v0 = bfu2f(vv4.x), v1 = bfu2f(vv4.y), v2 = bfu2f(vv4.z), v3 = bfu2f(vv4.w);

    float part[8];
    #pragma unroll
    for (int tt = 0; tt < 8; tt++){
        ushort4 ee = *(const ushort4*)(eb + tt*C2n + c0);
        part[tt] = v0*bfu2f(ee.x) + v1*bfu2f(ee.y) + v2*bfu2f(ee.z) + v3*bfu2f(ee.w);
    }
    __shared__ float red[8][4];
    int lane = threadIdx.x & 63, wid = threadIdx.x >> 6;
    #pragma unroll
    for (int tt = 0; tt < 8; tt++){
        float x = part[tt];
        for (int off = 32; off > 0; off >>= 1) x += __shfl_down(x, off);
        if (lane == 0) red[tt][wid] = x;
    }
    __syncthreads();
    float a[8]; float mx = -1e30f, sum = 0.f;
    #pragma unroll
    for (int tt = 0; tt < 8; tt++){
        float sv = red[tt][0] + red[tt][1] + red[tt][2] + red[tt][3];
        a[tt] = sv; mx = fmaxf(mx, sv);
    }
    #pragma unroll
    for (int tt = 0; tt < 8; tt++){ a[tt] = __expf(a[tt] - mx); sum += a[tt]; }
    float inv = 1.f / sum;
    #pragma unroll
    for (int tt = 0; tt < 8; tt++) a[tt] *= inv;

    float m0f = 0.f, m1f = 0.f, m2f = 0.f, m3f = 0.f;
    #pragma unroll
    for (int tt = 0; tt < 8; tt++){
        ushort4 ff = *(const ushort4*)(Fb + tt*C2n + c0);
        m0f += a[tt]*bfu2f(ff.x); m1f += a[tt]*bfu2f(ff.y);
        m2f += a[tt]*bfu2f(ff.z); m3f += a[tt]*bfu2f(ff.w);
    }
    ushort4 mm = *(const ushort4*)(morow + c0);
    float w = wpos[b*Sn + s];
    float o0 = (fmaxf(m0f + bfu2f(mm.x) + fc1_b[c0+0], 0.f) + v0) * w;
    float o1 = (fmaxf(m1f + bfu2f(mm.y) + fc1_b[c0+1], 0.f) + v1) * w;
    float o2 = (fmaxf(m2f + bfu2f(mm.z) + fc1_b[c0+2], 0.f) + v2) * w;
    float o3 = (fmaxf(m3f + bfu2f(mm.w) + fc1_b[c0+3], 0.f) + v3) * w;
    ushort4 outv;
    outv.x = f2bfu(o0); outv.y = f2bfu(o1); outv.z = f2bfu(o2); outv.w = f2bfu(o3);
    *(ushort4*)(vrow + c0) = outv;
}

// ---------------- conv1d(k=3,pad=1) + bias + relu + max over s ----------------
__global__ __launch_bounds__(128) void conv_kernel(
    const ushort_t* __restrict__ v, const float* __restrict__ cw,
    const float* __restrict__ cb, float* __restrict__ zmax)
{
    int o = blockIdx.x, b = blockIdx.y;
    __shared__ float wk[3][1024];
    for (int i = threadIdx.x; i < 3072; i += 128){
        wk[i % 3][i / 3] = cw[o*3072 + i];
    }
    __syncthreads();
    int s = threadIdx.x;
    float acc = 0.f;
    #pragma unroll
    for (int k = 0; k < 3; k++){
        int ss = s + k - 1;
        if (ss < 0 || ss >= Sn) continue;
        const ushort4* vr = (const ushort4*)(v + ((long)b*Sn + ss)*C2n);
        const float4* wr = (const float4*)(&wk[k][0]);
        float a0 = 0.f;
        for (int c4 = 0; c4 < 256; c4++){
            ushort4 vv = vr[c4]; float4 ww = wr[c4];
            a0 += bfu2f(vv.x)*ww.x + bfu2f(vv.y)*ww.y + bfu2f(vv.z)*ww.z + bfu2f(vv.w)*ww.w;
        }
        acc += a0;
    }
    acc = fmaxf(acc + cb[o], 0.f);
    __shared__ float red[128];
    red[s] = acc; __syncthreads();
    for (int off = 64; off > 0; off >>= 1){
        if (s < off) red[s] = fmaxf(red[s], red[s + off]);
        __syncthreads();
    }
    if (s == 0) zmax[b*NCONV + o] = red[0];
}

// ---------------- logits + log_softmax + NLL loss ----------------
__global__ __launch_bounds__(128) void loss_kernel(
    const float* __restrict__ zmax, const float* __restrict__ fcw,
    const float* __restrict__ fcb, const int* __restrict__ label,
    float* __restrict__ out)
{
    int b = threadIdx.x;
    float lg[3];
    #pragma unroll
    for (int l = 0; l < 3; l++){
        float a = fcb[l];
        for (int k = 0; k < NCONV; k++) a += zmax[b*NCONV + k] * fcw[l*NCONV + k];
        lg[l] = a;
        out[1 + b*3 + l] = a;
    }
    float mx = fmaxf(lg[0], fmaxf(lg[1], lg[2]));
    float sum = expf(lg[0]-mx) + expf(lg[1]-mx) + expf(lg[2]-mx);
    float lse = mx + logf(sum);
    float lp = lg[label[b]] - lse;
    __shared__ float red[128];
    red[b] = lp; __syncthreads();
    for (int off = 64; off > 0; off >>= 1){
        if (b < off) red[b] += red[b + off];
        __syncthreads();
    }
    if (b == 0) out[0] = -red[0] / (float)Bn;
}

extern "C" void kernel_launch(void* const* d_in, const int* in_sizes, int n_in,
                              void* d_out, int out_size, void* d_ws, size_t ws_size,
                              hipStream_t stream)
{
    (void)in_sizes; (void)n_in; (void)out_size; (void)ws_size;
    const int* raw_text  = (const int*)d_in[0];
    const int* target    = (const int*)d_in[1];
    const int* span      = (const int*)d_in[2];
    const int* label     = (const int*)d_in[3];
    const float* embW    = (const float*)d_in[4];
    const float* l1f_Wih = (const float*)d_in[5];
    const float* l1f_Whh = (const float*)d_in[6];
    const float* l1f_b   = (const float*)d_in[7];
    const float* l1b_Wih = (const float*)d_in[8];
    const float* l1b_Whh = (const float*)d_in[9];
    const float* l1b_b   = (const float*)d_in[10];
    const float* l2f_Wih = (const float*)d_in[11];
    const float* l2f_Whh = (const float*)d_in[12];
    const float* l2f_b   = (const float*)d_in[13];
    const float* l2b_Wih = (const float*)d_in[14];
    const float* l2b_Whh = (const float*)d_in[15];
    const float* l2b_b   = (const float*)d_in[16];
    const float* conv_w  = (const float*)d_in[17];
    const float* conv_b  = (const float*)d_in[18];
    const float* fc1_w   = (const float*)d_in[19];
    const float* fc1_b   = (const float*)d_in[20];
    const float* fc_w    = (const float*)d_in[21];
    const float* fc_b    = (const float*)d_in[22];

    float* ws = (float*)d_ws;
    ushort_t* Xf1  = (ushort_t*)(ws + OFF_X1C);
    ushort_t* Xb1  = Xf1 + 4194304;
    ushort_t* Xf2  = (ushort_t*)(ws + OFF_X2);
    ushort_t* Xb2  = Xf2 + 2097152;
    ushort_t* featb= (ushort_t*)(ws + OFF_FEAT);
    ushort_t* aspb = (ushort_t*)(ws + OFF_ASP);
    ushort_t* vbuf = (ushort_t*)(ws + OFF_V);
    ushort_t* ebuf = (ushort_t*)(ws + OFF_E);
    ushort_t* F2   = (ushort_t*)(ws + OFF_F2);
    ushort_t* mo   = (ushort_t*)(ws + OFF_MO);
    float* st  = ws + OFF_STATE;
    int* lenf  = (int*)(ws + OFF_LENF);
    int* lena  = (int*)(ws + OFF_LENA);
    int* rmF1  = (int*)(ws + OFF_RMF1);
    int* rmB1  = (int*)(ws + OFF_RMB1);
    int* rm2   = (int*)(ws + OFF_RM2);
    float* wpos= ws + OFF_WPOS;
    float* zmax= ws + OFF_ZMAX;

    float* h1A_f = st;              float* h1B_f = st + 65536;   float* c1_f = st + 131072;
    float* h1A_b = st + 196608;     float* h1B_b = st + 262144;  float* c1_b = st + 327680;
    float* st2 = st + 393216;
    float* h2A_f = st2;             float* h2B_f = st2 + 65536;  float* c2_f = st2 + 131072;
    float* h2A_b = st2 + 196608;    float* h2B_b = st2 + 262144; float* c2_b = st2 + 327680;

    zero_kernel<<<3072, 256, 0, stream>>>(st, 786432L);
    prep_kernel<<<Bn, 128, 0, stream>>>(raw_text, target, span, lenf, lena, rmF1, rmB1, rm2, wpos);
    embed_kernel<<<(Bn*Sn*En + 255)/256, 256, 0, stream>>>(raw_text, embW, featb, (long)Bn*Sn*En);
    embed_kernel<<<(Bn*Tn*En + 255)/256, 256, 0, stream>>>(target, embW, aspb, (long)Bn*Tn*En);

    // layer-1 biLSTM: chunked input projection + steps
    dim3 gc(Gn/64, (Bn*CH)/64);    // (32, 32)
    dim3 gl(Hn/32, Bn/32, 2);
    for (int c = 0; c < NCH; c++){
        gemm_bf16<<<gc, 256, 0, stream>>>(featb, En, rmF1 + c*Bn*CH, l1f_Wih, En, l1f_b, Xf1, Gn, Bn*CH, Gn, En);
        gemm_bf16<<<gc, 256, 0, stream>>>(featb, En, rmB1 + c*Bn*CH, l1b_Wih, En, l1b_b, Xb1, Gn, Bn*CH, Gn, En);
        for (int tt = 0; tt < CH; tt++){
            int t = c*CH + tt;
            const float* hpf = (t & 1) ? h1B_f : h1A_f;  float* hnf = (t & 1) ? h1A_f : h1B_f;
            const float* hpb = (t & 1) ? h1B_b : h1A_b;  float* hnb = (t & 1) ? h1A_b : h1B_b;
            lstm_step_kernel<<<gl, 256, 0, stream>>>(Xf1, Xb1, l1f_Whh, l1b_Whh,
                hpf, hpb, hnf, hnb, c1_f, c1_b, vbuf, lenf, t, tt, Sn, CH);
        }
    }
    // layer-2 biLSTM (T=8, unchunked)
    dim3 g2(Gn/64, (Bn*Tn)/64);    // (32, 16)
    gemm_bf16<<<g2, 256, 0, stream>>>(aspb, En, nullptr, l2f_Wih, En, l2f_b, Xf2, Gn, Bn*Tn, Gn, En);
    gemm_bf16<<<g2, 256, 0, stream>>>(aspb, En, rm2,     l2b_Wih, En, l2b_b, Xb2, Gn, Bn*Tn, Gn, En);
    for (int t = 0; t < Tn; t++){
        const float* hpf = (t & 1) ? h2B_f : h2A_f;  float* hnf = (t & 1) ? h2A_f : h2B_f;
        const float* hpb = (t & 1) ? h2B_b : h2A_b;  float* hnb = (t & 1) ? h2A_b : h2B_b;
        lstm_step_kernel<<<gl, 256, 0, stream>>>(Xf2, Xb2, l2f_Whh, l2b_Whh,
            hpf, hpb, hnf, hnb, c2_f, c2_b, ebuf, lena, t, t, Tn, Tn);
    }

    // F2[b,t,:] = e[b,t,:] @ W1^T (W1 = fc1_w[:, :1024]); e fixed across CPT iterations
    dim3 gF(C2n/64, (Bn*Tn)/64);   // (16, 16)
    gemm_bf16<<<gF, 256, 0, stream>>>(ebuf, C2n, nullptr, fc1_w, 2048, nullptr, F2, C2n, Bn*Tn, C2n, C2n);

    // 2 CPT iterations: mo = v @ W2^T, then fused attention/fc1/residual
    dim3 gm(C2n/64, (Bn*Sn)/64);   // (16, 256)
    for (int it = 0; it < 2; it++){
        gemm_bf16<<<gm, 256, 0, stream>>>(vbuf, C2n, nullptr, fc1_w + 1024, 2048, nullptr, mo, C2n, Bn*Sn, C2n, C2n);
        attn2_kernel<<<dim3(Sn, Bn), 256, 0, stream>>>(vbuf, ebuf, F2, mo, fc1_b, wpos);
    }

    conv_kernel<<<dim3(NCONV, Bn), 128, 0, stream>>>(vbuf, conv_w, conv_b, zmax);
    loss_kernel<<<1, 128, 0, stream>>>(zmax, fc_w, fc_b, label, (float*)d_out);
}

// Round 6
// 6183.911 us; speedup vs baseline: 1.2269x; 1.2269x over previous
//
#include <hip/hip_runtime.h>
#include <hip/hip_bf16.h>
#include <math.h>

#define Bn 128
#define Sn 128
#define Tn 8
#define En 300
#define EnP 320
#define Hn 512
#define Gn 2048
#define C2n 1024
#define NCONV 50
#define CH 16
#define NCH 8

typedef unsigned short ushort_t;
typedef __attribute__((ext_vector_type(8))) short bf16x8;
typedef __attribute__((ext_vector_type(4))) float f32x4;
typedef __attribute__((ext_vector_type(8))) unsigned short ushort8_t;

// ---------------- workspace layout (float-unit offsets, ~87.6 MB) ----------------
#define OFF_X1C   0L          // bf16 2*128*16*2048
#define OFF_X2    4194304L    // bf16 2*128*8*2048
#define OFF_FEATP 6291456L    // bf16 16384*320
#define OFF_ASPP  8912896L    // bf16 1024*320
#define OFF_WIH   9076736L    // 4 x bf16 2048*320
#define OFF_FC1WB 10387456L   // bf16 1024*2048
#define OFF_CWT   11436032L   // f32 50*3*1024
#define OFF_V     11589632L   // bf16 128*128*1024
#define OFF_E     19978240L   // bf16 128*8*1024
#define OFF_F2    20502528L   // bf16 128*8*1024
#define OFF_STATE 21026816L   // f32 786432
#define OFF_LENF  21813248L
#define OFF_LENA  21813376L
#define OFF_RMF1  21813504L
#define OFF_RMB1  21829888L
#define OFF_RM2   21846272L
#define OFF_WPOS  21847296L
#define OFF_ZPART 21863680L   // f32 128*50*4
#define WS_NEED_F 21889280L
#define OFF_MO    0L          // bf16 16,777,216 elems; reuses X1C+X2+FEATP (dead after LSTMs)

__device__ __forceinline__ float sigm_(float x){ return 1.f/(1.f + __expf(-x)); }
__device__ __forceinline__ float tanh_(float x){ return 2.f/(1.f + __expf(-2.f*x)) - 1.f; }
__device__ __forceinline__ float bfu2f(ushort_t u){ return __uint_as_float(((unsigned int)u) << 16); }
__device__ __forceinline__ ushort_t f2bfu(float f){
    __hip_bfloat16 h = __float2bfloat16(f);
    return *reinterpret_cast<ushort_t*>(&h);
}
__device__ __forceinline__ void gload16(const void* g, void* l){
    __builtin_amdgcn_global_load_lds(
        (const __attribute__((address_space(1))) void*)g,
        (__attribute__((address_space(3))) void*)l, 16, 0, 0);
}

// ---------------- zero ----------------
__global__ void zero_kernel(float* __restrict__ p, long n){
    long i = (long)blockIdx.x*256 + threadIdx.x;
    if (i < n) p[i] = 0.f;
}

// ---------------- prep ----------------
__global__ __launch_bounds__(128) void prep_kernel(
    const int* __restrict__ raw_text, const int* __restrict__ target,
    const int* __restrict__ span,
    int* __restrict__ lenf, int* __restrict__ lena,
    int* __restrict__ rmF1, int* __restrict__ rmB1, int* __restrict__ rm2,
    float* __restrict__ wpos)
{
    int b = blockIdx.x, tid = threadIdx.x;
    __shared__ int sh[128];
    sh[tid] = (raw_text[b*Sn + tid] != 0) ? 1 : 0;
    __syncthreads();
    for (int off = 64; off > 0; off >>= 1){
        if (tid < off) sh[tid] += sh[tid + off];
        __syncthreads();
    }
    __shared__ int lfs, las;
    if (tid == 0){
        lfs = sh[0]; lenf[b] = lfs;
        int c = 0;
        for (int tt = 0; tt < Tn; tt++) c += (target[b*Tn + tt] != 0) ? 1 : 0;
        las = c; lena[b] = c;
    }
    __syncthreads();
    int Lf = lfs, La = las;
    int t = tid;
    int c = t >> 4, tt = t & 15;
    int rev = (t < Lf) ? (Lf - 1 - t) : t;
    rmF1[(c*Bn + b)*CH + tt] = b*Sn + t;
    rmB1[(c*Bn + b)*CH + tt] = b*Sn + rev;
    if (t < Tn) rm2[b*Tn + t] = b*Tn + ((t < La) ? (La - 1 - t) : t);
    float p0 = (float)span[b*2 + 0], p1 = (float)span[b*2 + 1];
    float j = (float)t;
    wpos[b*Sn + t] = (j < p1) ? (1.0f - (p1 - j)/40.0f) : (1.0f - (j - p0)/40.0f);
}

// ---------------- embedding gather -> bf16, K padded 300->320 ----------------
__global__ void embed_kernel(const int* __restrict__ ids, const float* __restrict__ embW,
                             ushort_t* __restrict__ out, long rows)
{
    long i = (long)blockIdx.x*256 + threadIdx.x;
    if (i >= rows*EnP) return;
    long r = i / EnP; int c = (int)(i - r*EnP);
    out[i] = (c < En) ? f2bfu(embW[(long)ids[r]*En + c]) : (ushort_t)0;
}

// ---------------- f32 -> bf16 weight convert with K padding ----------------
__global__ void cvtpad_kernel(const float* __restrict__ src, ushort_t* __restrict__ dst,
                              int rows, int K, int Kp)
{
    long i = (long)blockIdx.x*256 + threadIdx.x;
    if (i >= (long)rows*Kp) return;
    int r = (int)(i / Kp), c = (int)(i - (long)r*Kp);
    dst[i] = (c < K) ? f2bfu(src[(long)r*K + c]) : (ushort_t)0;
}

// ---------------- conv weight transpose [o][c][k] -> [o][k][c] f32 ----------------
__global__ void convw_kernel(const float* __restrict__ cw, float* __restrict__ cwT){
    int i = blockIdx.x*256 + threadIdx.x;
    if (i >= NCONV*3*1024) return;
    int o = i / 3072, rem = i % 3072, k = rem / 1024, c = rem % 1024;
    cwT[i] = cw[o*3072 + c*3 + k];
}

// ---------------- MFMA GEMM: C[m,n] = bias[n] + sum_k A[rowmap(m),k]*Wb[n,k] ----------------
// A,Wb,C bf16; 128x128 tile, BK=32, 4 waves; global_load_lds staging with
// chunk-XOR swizzle (inverse-swz source + swz read, linear LDS dest).
__global__ __launch_bounds__(256) void mfma_gemm(
    const ushort_t* __restrict__ A, int lda, const int* __restrict__ rowmap,
    const ushort_t* __restrict__ Wb, int ldw, const float* __restrict__ bias,
    ushort_t* __restrict__ C, int ldc, int M, int N, int K)
{
    __shared__ ushort_t As[128*32];
    __shared__ ushort_t Bs[128*32];
    int tid = threadIdx.x;
    int lane = tid & 63, wid = tid >> 6;
    int m0 = blockIdx.y * 128, n0 = blockIdx.x * 128;
    int wr = wid >> 1, wc = wid & 1;

    // staging: slot s (16B) -> ms=s>>2, ch=s&3; thread covers slots tid and tid+256
    int ms0 = tid >> 2, ch0 = tid & 3;
    int arow0 = m0 + ms0, arow1 = m0 + ms0 + 64;
    if (rowmap){ arow0 = rowmap[arow0]; arow1 = rowmap[arow1]; }
    const ushort_t* Aptr0 = A + (long)arow0*lda;
    const ushort_t* Aptr1 = A + (long)arow1*lda;
    const ushort_t* Bptr0 = Wb + (long)(n0 + ms0)*ldw;
    const ushort_t* Bptr1 = Wb + (long)(n0 + ms0 + 64)*ldw;
    int swk = (ch0 ^ ((ms0 >> 1) & 3)) * 8;   // swizzled element offset (same for ms0+64)

    ushort_t* AsB0 = As + wid*512;            // wave-uniform LDS bases
    ushort_t* AsB1 = As + 2048 + wid*512;
    ushort_t* BsB0 = Bs + wid*512;
    ushort_t* BsB1 = Bs + 2048 + wid*512;

    f32x4 acc[4][4];
    #pragma unroll
    for (int i = 0; i < 4; i++)
        #pragma unroll
        for (int j = 0; j < 4; j++) acc[i][j] = (f32x4){0.f, 0.f, 0.f, 0.f};

    int r = lane & 15, g = lane >> 4;
    for (int kt = 0; kt < K; kt += 32){
        gload16(Aptr0 + kt + swk, AsB0);
        gload16(Aptr1 + kt + swk, AsB1);
        gload16(Bptr0 + kt + swk, BsB0);
        gload16(Bptr1 + kt + swk, BsB1);
        __syncthreads();
        bf16x8 af[4], bw[4];
        #pragma unroll
        for (int i = 0; i < 4; i++){
            int msA = wr*64 + i*16 + r;
            af[i] = *(const bf16x8*)(As + msA*32 + ((g ^ ((msA >> 1) & 3)) * 8));
            int msB = wc*64 + i*16 + r;
            bw[i] = *(const bf16x8*)(Bs + msB*32 + ((g ^ ((msB >> 1) & 3)) * 8));
        }
        #pragma unroll
        for (int i = 0; i < 4; i++)
            #pragma unroll
            for (int j = 0; j < 4; j++)
                acc[i][j] = __builtin_amdgcn_mfma_f32_16x16x32_bf16(af[i], bw[j], acc[i][j], 0, 0, 0);
        __syncthreads();
    }
    #pragma unroll
    for (int i = 0; i < 4; i++){
        int row = m0 + wr*64 + i*16 + g*4;
        #pragma unroll
        for (int j = 0; j < 4; j++){
            int col = n0 + wc*64 + j*16 + r;
            float bv = bias ? bias[col] : 0.f;
            #pragma unroll
            for (int q = 0; q < 4; q++)
                C[(long)(row + q)*ldc + col] = f2bfu(acc[i][j][q] + bv);
        }
    }
}

// ---------------- fused LSTM step (unchanged) ----------------
__global__ __launch_bounds__(256) void lstm_step_kernel(
    const ushort_t* __restrict__ Xf, const ushort_t* __restrict__ Xb,
    const float* __restrict__ Whf, const float* __restrict__ Whb,
    const float* __restrict__ hpf, const float* __restrict__ hpb,
    float* __restrict__ hnf, float* __restrict__ hnb,
    float* __restrict__ cfp, float* __restrict__ cbp,
    ushort_t* __restrict__ out, const int* __restrict__ lens,
    int t, int tloc, int Pout, int CHin)
{
    int dir = blockIdx.z;
    const ushort_t* X = dir ? Xb  : Xf;
    const float* Wh = dir ? Whb : Whf;
    const float* hp = dir ? hpb : hpf;
    float* hn = dir ? hnb : hnf;
    float* cc = dir ? cbp : cfp;

    int j0 = blockIdx.x * 32;
    int b0 = blockIdx.y * 32;
    int tid = threadIdx.x;
    int tx = tid & 15, ty = tid >> 4;

    __shared__ float Hs[16][32];
    __shared__ float Ws[16][128];

    float acc[4][2][2];
    #pragma unroll
    for (int g = 0; g < 4; g++){ acc[g][0][0]=0.f; acc[g][0][1]=0.f; acc[g][1][0]=0.f; acc[g][1][1]=0.f; }

    int hb = tid >> 3;
    int hk = (tid & 7) * 2;
    int wr = tid >> 1;
    int wg = wr >> 5;
    int wj = wr & 31;
    int wq = (tid & 1) * 8;
    const float* WhRow = Wh + (long)(wg*Hn + j0 + wj)*Hn;
    const float* hpRow = hp + (long)(b0 + hb)*Hn;

    for (int k0 = 0; k0 < Hn; k0 += 16){
        float2 hv = *(const float2*)(hpRow + k0 + hk);
        float4 wa = *(const float4*)(WhRow + k0 + wq);
        float4 wb = *(const float4*)(WhRow + k0 + wq + 4);
        __syncthreads();
        Hs[hk][hb] = hv.x; Hs[hk+1][hb] = hv.y;
        Ws[wq+0][wg*32+wj] = wa.x; Ws[wq+1][wg*32+wj] = wa.y;
        Ws[wq+2][wg*32+wj] = wa.z; Ws[wq+3][wg*32+wj] = wa.w;
        Ws[wq+4][wg*32+wj] = wb.x; Ws[wq+5][wg*32+wj] = wb.y;
        Ws[wq+6][wg*32+wj] = wb.z; Ws[wq+7][wg*32+wj] = wb.w;
        __syncthreads();
        #pragma unroll
        for (int kk = 0; kk < 16; kk++){
            float2 h2 = *(const float2*)&Hs[kk][ty*2];
            #pragma unroll
            for (int g = 0; g < 4; g++){
                float2 w2 = *(const float2*)&Ws[kk][g*32 + tx*2];
                acc[g][0][0] += h2.x*w2.x; acc[g][0][1] += h2.x*w2.y;
                acc[g][1][0] += h2.y*w2.x; acc[g][1][1] += h2.y*w2.y;
            }
        }
    }

    #pragma unroll
    for (int bb = 0; bb < 2; bb++){
        int b = b0 + ty*2 + bb;
        int len = lens[b];
        long xoff = ((long)b*CHin + tloc)*Gn;
        #pragma unroll
        for (int jj = 0; jj < 2; jj++){
            int j = j0 + tx*2 + jj;
            float gi = acc[0][bb][jj] + bfu2f(X[xoff + j]);
            float gf = acc[1][bb][jj] + bfu2f(X[xoff + Hn + j]);
            float gg = acc[2][bb][jj] + bfu2f(X[xoff + 2*Hn + j]);
            float go = acc[3][bb][jj] + bfu2f(X[xoff + 3*Hn + j]);
            float si = sigm_(gi), sf = sigm_(gf), tg = tanh_(gg), so = sigm_(go);
            int ci = b*Hn + j;
            float cn = sf*cc[ci] + si*tg;
            cc[ci] = cn;
            float hv = so * tanh_(cn);
            hn[ci] = hv;
            int pos = dir ? ((t < len) ? (len - 1 - t) : t) : t;
            float val = (t < len) ? hv : 0.f;
            out[((long)b*Pout + pos)*C2n + dir*Hn + j] = f2bfu(val);
        }
    }
}

// ---------------- fused attention + fc1 + residual + pos-weight (unchanged) ----------------
__global__ __launch_bounds__(256) void attn2_kernel(
    ushort_t* __restrict__ v, const ushort_t* __restrict__ e,
    const ushort_t* __restrict__ F2, const ushort_t* __restrict__ mo,
    const float* __restrict__ fc1_b, const float* __restrict__ wpos)
{
    int s = blockIdx.x, b = blockIdx.y;
    ushort_t* vrow = v + ((long)b*Sn + s)*C2n;
    const ushort_t* eb = e + (long)b*Tn*C2n;
    const ushort_t* Fb = F2 + (long)b*Tn*C2n;
    const ushort_t* morow = mo + ((long)b*Sn + s)*C2n;
    int c0 = threadIdx.x * 4;

    ushort4 vv4 = *(const ushort4*)(vrow + c0);
    float v0 = bfu2f(vv4.x), v1 = bfu2f(vv4.y), v2 = bfu2f(vv4.z), v3 = bfu2f(vv4.w);

    float part[8];
    #pragma unroll
    for (int tt = 0; tt < 8; tt++){
        ushort4 ee = *(const ushort4*)(eb + tt*C2n + c0);
        part[tt] = v0*bfu2f(ee.x) + v1*bfu2f(ee.y) + v2*bfu2f(ee.z) + v3*bfu2f(ee.w);
    }
    __shared__ float red[8][4];
    int lane = threadIdx.x & 63, wid = threadIdx.x >> 6;
    #pragma unroll
    for (int tt = 0; tt < 8; tt++){
        float x = part[tt];
        for (int off = 32; off > 0; off >>= 1) x += __shfl_down(x, off);
        if (lane == 0) red[tt][wid] = x;
    }
    __syncthreads();
    float a[8]; float mx = -1e30f, sum = 0.f;
    #pragma unroll
    for (int tt = 0; tt < 8; tt++){
        float sv = red[tt][0] + red[tt][1] + red[tt][2] + red[tt][3];
        a[tt] = sv; mx = fmaxf(mx, sv);
    }
    #pragma unroll
    for (int tt = 0; tt < 8; tt++){ a[tt] = __expf(a[tt] - mx); sum += a[tt]; }
    float inv = 1.f / sum;
    #pragma unroll
    for (int tt = 0; tt < 8; tt++) a[tt] *= inv;

    float m0f = 0.f, m1f = 0.f, m2f = 0.f, m3f = 0.f;
    #pragma unroll
    for (int tt = 0; tt < 8; tt++){
        ushort4 ff = *(const ushort4*)(Fb + tt*C2n + c0);
        m0f += a[tt]*bfu2f(ff.x); m1f += a[tt]*bfu2f(ff.y);
        m2f += a[tt]*bfu2f(ff.z); m3f += a[tt]*bfu2f(ff.w);
    }
    ushort4 mm = *(const ushort4*)(morow + c0);
    float w = wpos[b*Sn + s];
    float o0 = (fmaxf(m0f + bfu2f(mm.x) + fc1_b[c0+0], 0.f) + v0) * w;
    float o1 = (fmaxf(m1f + bfu2f(mm.y) + fc1_b[c0+1], 0.f) + v1) * w;
    float o2 = (fmaxf(m2f + bfu2f(mm.z) + fc1_b[c0+2], 0.f) + v2) * w;
    float o3 = (fmaxf(m3f + bfu2f(mm.w) + fc1_b[c0+3], 0.f) + v3) * w;
    ushort4 outv;
    outv.x = f2bfu(o0); outv.y = f2bfu(o1); outv.z = f2bfu(o2); outv.w = f2bfu(o3);
    *(ushort4*)(vrow + c0) = outv;
}

// ---------------- conv1d: LDS-staged v tile, all 50 o per block, partial max ----------------
__global__ __launch_bounds__(256) void conv2_kernel(
    const ushort_t* __restrict__ v, const float* __restrict__ cwT,
    const float* __restrict__ cb, float* __restrict__ zpart)
{
    int st = blockIdx.x, b = blockIdx.y;
    int s0 = st * 32;
    __shared__ ushort_t vs[34*1024];
    for (int i = threadIdx.x; i < 34*128; i += 256){
        int rr = i >> 7, ck = i & 127;
        int ss = s0 - 1 + rr;
        ushort8_t val = {0,0,0,0,0,0,0,0};
        if (ss >= 0 && ss < Sn) val = *(const ushort8_t*)(v + ((long)b*Sn + ss)*C2n + ck*8);
        *(ushort8_t*)(vs + rr*1024 + ck*8) = val;
    }
    __syncthreads();
    int sl = threadIdx.x & 31, ob = threadIdx.x >> 5;
    for (int o = ob; o < NCONV; o += 8){
        float acc = cb[o];
        #pragma unroll
        for (int k = 0; k < 3; k++){
            const ushort_t* vrow = vs + (sl + k)*1024;
            const float* wrow = cwT + (o*3 + k)*1024;
            float a0 = 0.f;
            for (int c8 = 0; c8 < 128; c8++){
                ushort8_t vv = *(const ushort8_t*)(vrow + c8*8);
                float4 wa = *(const float4*)(wrow + c8*8);
                float4 wb = *(const float4*)(wrow + c8*8 + 4);
                a0 += bfu2f(vv[0])*wa.x + bfu2f(vv[1])*wa.y + bfu2f(vv[2])*wa.z + bfu2f(vv[3])*wa.w
                    + bfu2f(vv[4])*wb.x + bfu2f(vv[5])*wb.y + bfu2f(vv[6])*wb.z + bfu2f(vv[7])*wb.w;
            }
            acc += a0;
        }
        float rv = fmaxf(acc, 0.f);
        for (int off = 16; off > 0; off >>= 1) rv = fmaxf(rv, __shfl_down(rv, off));
        if (sl == 0) zpart[((long)b*NCONV + o)*4 + st] = rv;
    }
}

// ---------------- logits + log_softmax + NLL loss (max over zpart) ----------------
__global__ __launch_bounds__(128) void loss_kernel(
    const float* __restrict__ zpart, const float* __restrict__ fcw,
    const float* __restrict__ fcb, const int* __restrict__ label,
    float* __restrict__ out)
{
    int b = threadIdx.x;
    float lg0 = fcb[0], lg1 = fcb[1], lg2 = fcb[2];
    for (int k = 0; k < NCONV; k++){
        const float* zp = zpart + ((long)b*NCONV + k)*4;
        float zm = fmaxf(fmaxf(zp[0], zp[1]), fmaxf(zp[2], zp[3]));
        lg0 += zm * fcw[k];
        lg1 += zm * fcw[NCONV + k];
        lg2 += zm * fcw[2*NCONV + k];
    }
    out[1 + b*3 + 0] = lg0;
    out[1 + b*3 + 1] = lg1;
    out[1 + b*3 + 2] = lg2;
    float mx = fmaxf(lg0, fmaxf(lg1, lg2));
    float sum = expf(lg0-mx) + expf(lg1-mx) + expf(lg2-mx);
    float lse = mx + logf(sum);
    int lb = label[b];
    float lp = ((lb == 0) ? lg0 : (lb == 1) ? lg1 : lg2) - lse;
    __shared__ float red[128];
    red[b] = lp; __syncthreads();
    for (int off = 64; off > 0; off >>= 1){
        if (b < off) red[b] += red[b + off];
        __syncthreads();
    }
    if (b == 0) out[0] = -red[0] / (float)Bn;
}

extern "C" void kernel_launch(void* const* d_in, const int* in_sizes, int n_in,
                              void* d_out, int out_size, void* d_ws, size_t ws_size,
                              hipStream_t stream)
{
    (void)in_sizes; (void)n_in; (void)out_size;
    if (ws_size < (size_t)WS_NEED_F * 4) return;   // visible absmax failure, not a fault
    const int* raw_text  = (const int*)d_in[0];
    const int* target    = (const int*)d_in[1];
    const int* span      = (const int*)d_in[2];
    const int* label     = (const int*)d_in[3];
    const float* embW    = (const float*)d_in[4];
    const float* l1f_Wih = (const float*)d_in[5];
    const float* l1f_Whh = (const float*)d_in[6];
    const float* l1f_b   = (const float*)d_in[7];
    const float* l1b_Wih = (const float*)d_in[8];
    const float* l1b_Whh = (const float*)d_in[9];
    const float* l1b_b   = (const float*)d_in[10];
    const float* l2f_Wih = (const float*)d_in[11];
    const float* l2f_Whh = (const float*)d_in[12];
    const float* l2f_b   = (const float*)d_in[13];
    const float* l2b_Wih = (const float*)d_in[14];
    const float* l2b_Whh = (const float*)d_in[15];
    const float* l2b_b   = (const float*)d_in[16];
    const float* conv_w  = (const float*)d_in[17];
    const float* conv_b  = (const float*)d_in[18];
    const float* fc1_w   = (const float*)d_in[19];
    const float* fc1_b   = (const float*)d_in[20];
    const float* fc_w    = (const float*)d_in[21];
    const float* fc_b    = (const float*)d_in[22];

    float* ws = (float*)d_ws;
    ushort_t* Xf1   = (ushort_t*)(ws + OFF_X1C);
    ushort_t* Xb1   = Xf1 + 4194304;
    ushort_t* Xf2   = (ushort_t*)(ws + OFF_X2);
    ushort_t* Xb2   = Xf2 + 2097152;
    ushort_t* featp = (ushort_t*)(ws + OFF_FEATP);
    ushort_t* aspp  = (ushort_t*)(ws + OFF_ASPP);
    ushort_t* WihF1 = (ushort_t*)(ws + OFF_WIH);
    ushort_t* WihB1 = WihF1 + 655360;
    ushort_t* WihF2 = WihF1 + 2*655360;
    ushort_t* WihB2 = WihF1 + 3*655360;
    ushort_t* fc1wb = (ushort_t*)(ws + OFF_FC1WB);
    float*    cwT   = ws + OFF_CWT;
    ushort_t* vbuf  = (ushort_t*)(ws + OFF_V);
    ushort_t* ebuf  = (ushort_t*)(ws + OFF_E);
    ushort_t* F2b   = (ushort_t*)(ws + OFF_F2);
    ushort_t* mo    = (ushort_t*)(ws + OFF_MO);
    float* st   = ws + OFF_STATE;
    int* lenf   = (int*)(ws + OFF_LENF);
    int* lena   = (int*)(ws + OFF_LENA);
    int* rmF1   = (int*)(ws + OFF_RMF1);
    int* rmB1   = (int*)(ws + OFF_RMB1);
    int* rm2    = (int*)(ws + OFF_RM2);
    float* wpos = ws + OFF_WPOS;
    float* zpart= ws + OFF_ZPART;

    float* h1A_f = st;              float* h1B_f = st + 65536;   float* c1_f = st + 131072;
    float* h1A_b = st + 196608;     float* h1B_b = st + 262144;  float* c1_b = st + 327680;
    float* st2 = st + 393216;
    float* h2A_f = st2;             float* h2B_f = st2 + 65536;  float* c2_f = st2 + 131072;
    float* h2A_b = st2 + 196608;    float* h2B_b = st2 + 262144; float* c2_b = st2 + 327680;

    zero_kernel<<<3072, 256, 0, stream>>>(st, 786432L);
    prep_kernel<<<Bn, 128, 0, stream>>>(raw_text, target, span, lenf, lena, rmF1, rmB1, rm2, wpos);
    embed_kernel<<<(Bn*Sn*EnP + 255)/256, 256, 0, stream>>>(raw_text, embW, featp, (long)Bn*Sn);
    embed_kernel<<<(Bn*Tn*EnP + 255)/256, 256, 0, stream>>>(target, embW, aspp, (long)Bn*Tn);

    // weight conversions
    cvtpad_kernel<<<(Gn*EnP + 255)/256, 256, 0, stream>>>(l1f_Wih, WihF1, Gn, En, EnP);
    cvtpad_kernel<<<(Gn*EnP + 255)/256, 256, 0, stream>>>(l1b_Wih, WihB1, Gn, En, EnP);
    cvtpad_kernel<<<(Gn*EnP + 255)/256, 256, 0, stream>>>(l2f_Wih, WihF2, Gn, En, EnP);
    cvtpad_kernel<<<(Gn*EnP + 255)/256, 256, 0, stream>>>(l2b_Wih, WihB2, Gn, En, EnP);
    cvtpad_kernel<<<(1024*2048 + 255)/256, 256, 0, stream>>>(fc1_w, fc1wb, 1024, 2048, 2048);
    convw_kernel<<<(NCONV*3072 + 255)/256, 256, 0, stream>>>(conv_w, cwT);

    // layer-1 biLSTM: chunked MFMA input projection + steps
    dim3 gc(Gn/128, (Bn*CH)/128);   // (16, 16)
    dim3 gl(Hn/32, Bn/32, 2);
    for (int c = 0; c < NCH; c++){
        mfma_gemm<<<gc, 256, 0, stream>>>(featp, EnP, rmF1 + c*Bn*CH, WihF1, EnP, l1f_b, Xf1, Gn, Bn*CH, Gn, EnP);
        mfma_gemm<<<gc, 256, 0, stream>>>(featp, EnP, rmB1 + c*Bn*CH, WihB1, EnP, l1b_b, Xb1, Gn, Bn*CH, Gn, EnP);
        for (int tt = 0; tt < CH; tt++){
            int t = c*CH + tt;
            const float* hpf = (t & 1) ? h1B_f : h1A_f;  float* hnf = (t & 1) ? h1A_f : h1B_f;
            const float* hpb = (t & 1) ? h1B_b : h1A_b;  float* hnb = (t & 1) ? h1A_b : h1B_b;
            lstm_step_kernel<<<gl, 256, 0, stream>>>(Xf1, Xb1, l1f_Whh, l1b_Whh,
                hpf, hpb, hnf, hnb, c1_f, c1_b, vbuf, lenf, t, tt, Sn, CH);
        }
    }
    // layer-2 biLSTM
    dim3 g2(Gn/128, (Bn*Tn)/128);   // (16, 8)
    mfma_gemm<<<g2, 256, 0, stream>>>(aspp, EnP, nullptr, WihF2, EnP, l2f_b, Xf2, Gn, Bn*Tn, Gn, EnP);
    mfma_gemm<<<g2, 256, 0, stream>>>(aspp, EnP, rm2,     WihB2, EnP, l2b_b, Xb2, Gn, Bn*Tn, Gn, EnP);
    for (int t = 0; t < Tn; t++){
        const float* hpf = (t & 1) ? h2B_f : h2A_f;  float* hnf = (t & 1) ? h2A_f : h2B_f;
        const float* hpb = (t & 1) ? h2B_b : h2A_b;  float* hnb = (t & 1) ? h2A_b : h2B_b;
        lstm_step_kernel<<<gl, 256, 0, stream>>>(Xf2, Xb2, l2f_Whh, l2b_Whh,
            hpf, hpb, hnf, hnb, c2_f, c2_b, ebuf, lena, t, t, Tn, Tn);
    }

    // F2 = e @ W1^T  (fc1_w cols 0..1023)
    dim3 gF(C2n/128, (Bn*Tn)/128);  // (8, 8)
    mfma_gemm<<<gF, 256, 0, stream>>>(ebuf, C2n, nullptr, fc1wb, 2048, nullptr, F2b, C2n, Bn*Tn, C2n, C2n);

    // 2 CPT iterations: mo = v @ W2^T, then fused attention/fc1/residual
    dim3 gm(C2n/128, (Bn*Sn)/128);  // (8, 128)
    for (int it = 0; it < 2; it++){
        mfma_gemm<<<gm, 256, 0, stream>>>(vbuf, C2n, nullptr, fc1wb + 1024, 2048, nullptr, mo, C2n, Bn*Sn, C2n, C2n);
        attn2_kernel<<<dim3(Sn, Bn), 256, 0, stream>>>(vbuf, ebuf, F2b, mo, fc1_b, wpos);
    }

    conv2_kernel<<<dim3(4, Bn), 256, 0, stream>>>(vbuf, cwT, conv_b, zpart);
    loss_kernel<<<1, 128, 0, stream>>>(zpart, fc_w, fc_b, label, (float*)d_out);
}

// Round 8
// 2847.954 us; speedup vs baseline: 2.6641x; 2.1714x over previous
//
#include <hip/hip_runtime.h>
#include <hip/hip_bf16.h>
#include <math.h>

#define Bn 128
#define Sn 128
#define Tn 8
#define En 300
#define EnP 320
#define Hn 512
#define Gn 2048
#define C2n 1024
#define NCONV 50
#define CH 16
#define NCH 8

typedef unsigned short ushort_t;
typedef __attribute__((ext_vector_type(8))) short bf16x8;
typedef __attribute__((ext_vector_type(4))) float f32x4;
typedef __attribute__((ext_vector_type(8))) unsigned short ushort8_t;

// ---------------- workspace layout (float-unit offsets, ~86.5 MB) ----------------
#define OFF_X1C   0L          // bf16 2*128*16*2048 = 8,388,608 ush
#define OFF_X2    4194304L    // bf16 4,194,304 ush
#define OFF_FEATP 6291456L    // bf16 16384*320
#define OFF_ASPP  8912896L    // bf16 1024*320
#define OFF_WIHI  9076736L    // bf16 4 x 2048*320 (gate-interleaved rows)
#define OFF_BIASI 10387456L   // f32 4 x 2048 (gate-interleaved)
#define OFF_FC1WB 10395648L   // bf16 1024*2048
#define OFF_CWT   11444224L   // f32 50*3*1024
#define OFF_V     11597824L   // bf16 128*128*1024
#define OFF_E     19986432L   // bf16 128*8*1024
#define OFF_F2    20510720L   // bf16 128*8*1024
#define OFF_STATE 21035008L   // f32 524288 (2 layers x {hA,hB bf16, c f32})
#define OFF_LENF  21559296L
#define OFF_LENA  21559424L
#define OFF_RMF1  21559552L
#define OFF_RMB1  21575936L
#define OFF_RM2   21592320L
#define OFF_WPOS  21593344L
#define OFF_ZPART 21609728L   // f32 128*50*4
#define WS_NEED_F 21635328L
#define OFF_MO    0L          // bf16 16,777,216 ush; reuses X1C+X2+FEATP (dead after LSTMs)

__device__ __forceinline__ float sigm_(float x){ return 1.f/(1.f + __expf(-x)); }
__device__ __forceinline__ float tanh_(float x){ return 2.f/(1.f + __expf(-2.f*x)) - 1.f; }
__device__ __forceinline__ float bfu2f(ushort_t u){ return __uint_as_float(((unsigned int)u) << 16); }
__device__ __forceinline__ ushort_t f2bfu(float f){
    __hip_bfloat16 h = __float2bfloat16(f);
    return *reinterpret_cast<ushort_t*>(&h);
}
__device__ __forceinline__ void gload16(const void* g, void* l){
    __builtin_amdgcn_global_load_lds(
        (const __attribute__((address_space(1))) void*)g,
        (__attribute__((address_space(3))) void*)l, 16, 0, 0);
}

// ---------------- zero ----------------
__global__ void zero_kernel(float* __restrict__ p, long n){
    long i = (long)blockIdx.x*256 + threadIdx.x;
    if (i < n) p[i] = 0.f;
}

// ---------------- prep ----------------
__global__ __launch_bounds__(128) void prep_kernel(
    const int* __restrict__ raw_text, const int* __restrict__ target,
    const int* __restrict__ span,
    int* __restrict__ lenf, int* __restrict__ lena,
    int* __restrict__ rmF1, int* __restrict__ rmB1, int* __restrict__ rm2,
    float* __restrict__ wpos)
{
    int b = blockIdx.x, tid = threadIdx.x;
    __shared__ int sh[128];
    sh[tid] = (raw_text[b*Sn + tid] != 0) ? 1 : 0;
    __syncthreads();
    for (int off = 64; off > 0; off >>= 1){
        if (tid < off) sh[tid] += sh[tid + off];
        __syncthreads();
    }
    __shared__ int lfs, las;
    if (tid == 0){
        lfs = sh[0]; lenf[b] = lfs;
        int c = 0;
        for (int tt = 0; tt < Tn; tt++) c += (target[b*Tn + tt] != 0) ? 1 : 0;
        las = c; lena[b] = c;
    }
    __syncthreads();
    int Lf = lfs, La = las;
    int t = tid;
    int c = t >> 4, tt = t & 15;
    int rev = (t < Lf) ? (Lf - 1 - t) : t;
    rmF1[(c*Bn + b)*CH + tt] = b*Sn + t;
    rmB1[(c*Bn + b)*CH + tt] = b*Sn + rev;
    if (t < Tn) rm2[b*Tn + t] = b*Tn + ((t < La) ? (La - 1 - t) : t);
    float p0 = (float)span[b*2 + 0], p1 = (float)span[b*2 + 1];
    float j = (float)t;
    wpos[b*Sn + t] = (j < p1) ? (1.0f - (p1 - j)/40.0f) : (1.0f - (j - p0)/40.0f);
}

// ---------------- embedding gather -> bf16, K padded 300->320 ----------------
__global__ void embed_kernel(const int* __restrict__ ids, const float* __restrict__ embW,
                             ushort_t* __restrict__ out, long rows)
{
    long i = (long)blockIdx.x*256 + threadIdx.x;
    if (i >= rows*EnP) return;
    long r = i / EnP; int c = (int)(i - r*EnP);
    out[i] = (c < En) ? f2bfu(embW[(long)ids[r]*En + c]) : (ushort_t)0;
}

// ---------------- Wih convert: f32 [2048][300] -> bf16 gate-interleaved [jr][320] ----------------
__global__ void cvtpad_inter(const float* __restrict__ src, ushort_t* __restrict__ dst){
    long i = (long)blockIdx.x*256 + threadIdx.x;
    if (i >= (long)Gn*EnP) return;
    int jr = (int)(i / EnP), c = (int)(i - (long)jr*EnP);
    dst[i] = (c < En) ? f2bfu(src[(long)((jr&3)*Hn + (jr>>2))*En + c]) : (ushort_t)0;
}

// ---------------- bias reorder to gate-interleaved ----------------
__global__ void bias_inter(const float* __restrict__ src, float* __restrict__ dst){
    int i = blockIdx.x*256 + threadIdx.x;
    if (i >= Gn) return;
    dst[i] = src[(i&3)*Hn + (i>>2)];
}

// ---------------- f32 -> bf16 plain convert (fc1_w) ----------------
__global__ void cvtpad_kernel(const float* __restrict__ src, ushort_t* __restrict__ dst,
                              int rows, int K, int Kp)
{
    long i = (long)blockIdx.x*256 + threadIdx.x;
    if (i >= (long)rows*Kp) return;
    int r = (int)(i / Kp), c = (int)(i - (long)r*Kp);
    dst[i] = (c < K) ? f2bfu(src[(long)r*K + c]) : (ushort_t)0;
}

// ---------------- conv weight transpose [o][c][k] -> [o][k][c] f32 ----------------
__global__ void convw_kernel(const float* __restrict__ cw, float* __restrict__ cwT){
    int i = blockIdx.x*256 + threadIdx.x;
    if (i >= NCONV*3*1024) return;
    int o = i / 3072, rem = i % 3072, k = rem / 1024, c = rem % 1024;
    cwT[i] = cw[o*3072 + c*3 + k];
}

// ---------------- MFMA GEMM (verified r4/r6): C = bias + A[rowmap]·W^T ----------------
__global__ __launch_bounds__(256) void mfma_gemm(
    const ushort_t* __restrict__ A, int lda, const int* __restrict__ rowmap,
    const ushort_t* __restrict__ Wb, int ldw, const float* __restrict__ bias,
    ushort_t* __restrict__ C, int ldc, int M, int N, int K)
{
    __shared__ ushort_t As[128*32];
    __shared__ ushort_t Bs[128*32];
    int tid = threadIdx.x;
    int lane = tid & 63, wid = tid >> 6;
    int m0 = blockIdx.y * 128, n0 = blockIdx.x * 128;
    int wr = wid >> 1, wc = wid & 1;

    int ms0 = tid >> 2, ch0 = tid & 3;
    int arow0 = m0 + ms0, arow1 = m0 + ms0 + 64;
    if (rowmap){ arow0 = rowmap[arow0]; arow1 = rowmap[arow1]; }
    const ushort_t* Aptr0 = A + (long)arow0*lda;
    const ushort_t* Aptr1 = A + (long)arow1*lda;
    const ushort_t* Bptr0 = Wb + (long)(n0 + ms0)*ldw;
    const ushort_t* Bptr1 = Wb + (long)(n0 + ms0 + 64)*ldw;
    int swk = (ch0 ^ ((ms0 >> 1) & 3)) * 8;

    ushort_t* AsB0 = As + wid*512;
    ushort_t* AsB1 = As + 2048 + wid*512;
    ushort_t* BsB0 = Bs + wid*512;
    ushort_t* BsB1 = Bs + 2048 + wid*512;

    f32x4 acc[4][4];
    #pragma unroll
    for (int i = 0; i < 4; i++)
        #pragma unroll
        for (int j = 0; j < 4; j++) acc[i][j] = (f32x4){0.f, 0.f, 0.f, 0.f};

    int r = lane & 15, g = lane >> 4;
    for (int kt = 0; kt < K; kt += 32){
        gload16(Aptr0 + kt + swk, AsB0);
        gload16(Aptr1 + kt + swk, AsB1);
        gload16(Bptr0 + kt + swk, BsB0);
        gload16(Bptr1 + kt + swk, BsB1);
        __syncthreads();
        bf16x8 af[4], bw[4];
        #pragma unroll
        for (int i = 0; i < 4; i++){
            int msA = wr*64 + i*16 + r;
            af[i] = *(const bf16x8*)(As + msA*32 + ((g ^ ((msA >> 1) & 3)) * 8));
            int msB = wc*64 + i*16 + r;
            bw[i] = *(const bf16x8*)(Bs + msB*32 + ((g ^ ((msB >> 1) & 3)) * 8));
        }
        #pragma unroll
        for (int i = 0; i < 4; i++)
            #pragma unroll
            for (int j = 0; j < 4; j++)
                acc[i][j] = __builtin_amdgcn_mfma_f32_16x16x32_bf16(af[i], bw[j], acc[i][j], 0, 0, 0);
        __syncthreads();
    }
    #pragma unroll
    for (int i = 0; i < 4; i++){
        int row = m0 + wr*64 + i*16 + g*4;
        #pragma unroll
        for (int j = 0; j < 4; j++){
            int col = n0 + wc*64 + j*16 + r;
            float bv = bias ? bias[col] : 0.f;
            #pragma unroll
            for (int q = 0; q < 4; q++)
                C[(long)(row + q)*ldc + col] = f2bfu(acc[i][j][q] + bv);
        }
    }
}

// ---------------- MFMA LSTM step ----------------
// grid (32 j-slices, 2 dirs), 256 thr. Block computes C[64 gaterows x 128 b] = Whh'·h^T.
// Gate-interleaved rows (jr=j*4+g) => f32x4 acc quad = {i,f,g,o} for one (j,b) in-register.
__global__ __launch_bounds__(256) void lstm_step2(
    const float* __restrict__ WhF, const float* __restrict__ WhB,
    const ushort_t* __restrict__ Xf, const ushort_t* __restrict__ Xb,
    const ushort_t* __restrict__ hprev, ushort_t* __restrict__ hnext,
    float* __restrict__ cst, ushort_t* __restrict__ out,
    const int* __restrict__ lens, int t, int tloc, int Pout, int CHin)
{
    int dir = blockIdx.y;
    const float* Wh = dir ? WhB : WhF;
    const ushort_t* X = dir ? Xb : Xf;
    const ushort_t* hp = hprev + dir*65536;
    ushort_t* hn = hnext + dir*65536;
    float* cc = cst + dir*65536;
    int j0 = blockIdx.x * 16;
    int tid = threadIdx.x, lane = tid & 63, wv = tid >> 6;
    int r15 = lane & 15, kg = lane >> 4;

    __shared__ ushort_t Ws[64*512];   // 64KB, XOR-swizzled
    __shared__ ushort_t Hs[128*32];   // 8KB, linear (banks balanced)

    // stage Whh slice: f32 -> bf16, interleaved rows, chunk-XOR swizzle
    #pragma unroll
    for (int it = 0; it < 16; it++){
        int id = it*256 + tid;
        int row = id >> 6, ch = id & 63;
        const float* src = Wh + (long)((row&3)*Hn + j0 + (row>>2))*Hn + ch*8;
        float4 f0 = *(const float4*)src;
        float4 f1 = *(const float4*)(src + 4);
        ushort8_t w8;
        w8[0]=f2bfu(f0.x); w8[1]=f2bfu(f0.y); w8[2]=f2bfu(f0.z); w8[3]=f2bfu(f0.w);
        w8[4]=f2bfu(f1.x); w8[5]=f2bfu(f1.y); w8[6]=f2bfu(f1.z); w8[7]=f2bfu(f1.w);
        *(ushort8_t*)(Ws + row*512 + ((ch ^ (row&7))*8)) = w8;
    }

    f32x4 acc[4][2];
    #pragma unroll
    for (int i = 0; i < 4; i++){ acc[i][0] = (f32x4){0.f,0.f,0.f,0.f}; acc[i][1] = (f32x4){0.f,0.f,0.f,0.f}; }

    int sb = tid >> 2, sc = (tid & 3)*8;
    for (int kt = 0; kt < 16; kt++){
        gload16(hp + sb*512 + kt*32 + sc,        Hs + wv*512);
        gload16(hp + (64+sb)*512 + kt*32 + sc,   Hs + 2048 + wv*512);
        __syncthreads();
        bf16x8 af[4], bfr[2];
        #pragma unroll
        for (int i = 0; i < 4; i++){
            int row = i*16 + r15;
            af[i] = *(const bf16x8*)(Ws + row*512 + (((kt*4 + kg) ^ (row&7))*8));
        }
        #pragma unroll
        for (int jc = 0; jc < 2; jc++){
            int b = wv*32 + jc*16 + r15;
            bfr[jc] = *(const bf16x8*)(Hs + b*32 + kg*8);
        }
        #pragma unroll
        for (int i = 0; i < 4; i++)
            #pragma unroll
            for (int jc = 0; jc < 2; jc++)
                acc[i][jc] = __builtin_amdgcn_mfma_f32_16x16x32_bf16(af[i], bfr[jc], acc[i][jc], 0, 0, 0);
        __syncthreads();
    }

    #pragma unroll
    for (int i = 0; i < 4; i++){
        int rowq = i*16 + kg*4;           // local gaterow quad base (j*4)
        int j = j0 + (rowq >> 2);
        #pragma unroll
        for (int jc = 0; jc < 2; jc++){
            int b = wv*32 + jc*16 + r15;
            int len = lens[b];
            ushort4 xg = *(const ushort4*)(X + (((long)(b*CHin + tloc)) << 11) + (j0 << 2) + rowq);
            float gi = acc[i][jc][0] + bfu2f(xg.x);
            float gf = acc[i][jc][1] + bfu2f(xg.y);
            float gg = acc[i][jc][2] + bfu2f(xg.z);
            float go = acc[i][jc][3] + bfu2f(xg.w);
            int ci = b*Hn + j;
            float cn = sigm_(gf)*cc[ci] + sigm_(gi)*tanh_(gg);
            cc[ci] = cn;
            float hv = sigm_(go)*tanh_(cn);
            hn[ci] = f2bfu(hv);
            int pos = dir ? ((t < len) ? (len - 1 - t) : t) : t;
            out[((long)b*Pout + pos)*C2n + dir*Hn + j] = (t < len) ? f2bfu(hv) : (ushort_t)0;
        }
    }
}

// ---------------- fused attention + fc1 + residual + pos-weight ----------------
__global__ __launch_bounds__(256) void attn2_kernel(
    ushort_t* __restrict__ v, const ushort_t* __restrict__ e,
    const ushort_t* __restrict__ F2, const ushort_t* __restrict__ mo,
    const float* __restrict__ fc1_b, const float* __restrict__ wpos)
{
    int s = blockIdx.x, b = blockIdx.y;
    ushort_t* vrow = v + ((long)b*Sn + s)*C2n;
    const ushort_t* eb = e + (long)b*Tn*C2n;
    const ushort_t* Fb = F2 + (long)b*Tn*C2n;
    const ushort_t* morow = mo + ((long)b*Sn + s)*C2n;
    int c0 = threadIdx.x * 4;

    ushort4 vv4 = *(const ushort4*)(vrow + c0);
    float v0 = bfu2f(vv4.x), v1 = bfu2f(vv4.y), v2 = bfu2f(vv4.z), v3 = bfu2f(vv4.w);

    float part[8];
    #pragma unroll
    for (int tt = 0; tt < 8; tt++){
        ushort4 ee = *(const ushort4*)(eb + tt*C2n + c0);
        part[tt] = v0*bfu2f(ee.x) + v1*bfu2f(ee.y) + v2*bfu2f(ee.z) + v3*bfu2f(ee.w);
    }
    __shared__ float red[8][4];
    int lane = threadIdx.x & 63, wid = threadIdx.x >> 6;
    #pragma unroll
    for (int tt = 0; tt < 8; tt++){
        float x = part[tt];
        for (int off = 32; off > 0; off >>= 1) x += __shfl_down(x, off);
        if (lane == 0) red[tt][wid] = x;
    }
    __syncthreads();
    float a[8]; float mx = -1e30f, sum = 0.f;
    #pragma unroll
    for (int tt = 0; tt < 8; tt++){
        float sv = red[tt][0] + red[tt][1] + red[tt][2] + red[tt][3];
        a[tt] = sv; mx = fmaxf(mx, sv);
    }
    #pragma unroll
    for (int tt = 0; tt < 8; tt++){ a[tt] = __expf(a[tt] - mx); sum += a[tt]; }
    float inv = 1.f / sum;
    #pragma unroll
    for (int tt = 0; tt < 8; tt++) a[tt] *= inv;

    float m0f = 0.f, m1f = 0.f, m2f = 0.f, m3f = 0.f;
    #pragma unroll
    for (int tt = 0; tt < 8; tt++){
        ushort4 ff = *(const ushort4*)(Fb + tt*C2n + c0);
        m0f += a[tt]*bfu2f(ff.x); m1f += a[tt]*bfu2f(ff.y);
        m2f += a[tt]*bfu2f(ff.z); m3f += a[tt]*bfu2f(ff.w);
    }
    ushort4 mm = *(const ushort4*)(morow + c0);
    float w = wpos[b*Sn + s];
    float o0 = (fmaxf(m0f + bfu2f(mm.x) + fc1_b[c0+0], 0.f) + v0) * w;
    float o1 = (fmaxf(m1f + bfu2f(mm.y) + fc1_b[c0+1], 0.f) + v1) * w;
    float o2 = (fmaxf(m2f + bfu2f(mm.z) + fc1_b[c0+2], 0.f) + v2) * w;
    float o3 = (fmaxf(m3f + bfu2f(mm.w) + fc1_b[c0+3], 0.f) + v3) * w;
    ushort4 outv;
    outv.x = f2bfu(o0); outv.y = f2bfu(o1); outv.z = f2bfu(o2); outv.w = f2bfu(o3);
    *(ushort4*)(vrow + c0) = outv;
}

// ---------------- conv1d: LDS-staged v tile (XOR-swizzled), all 50 o, partial max ----------------
__global__ __launch_bounds__(256) void conv2_kernel(
    const ushort_t* __restrict__ v, const float* __restrict__ cwT,
    const float* __restrict__ cb, float* __restrict__ zpart)
{
    int st = blockIdx.x, b = blockIdx.y;
    int s0 = st * 32;
    __shared__ ushort_t vs[34*1024];
    for (int i = threadIdx.x; i < 34*128; i += 256){
        int rr = i >> 7, ck = i & 127;
        int ss = s0 - 1 + rr;
        ushort8_t val = {0,0,0,0,0,0,0,0};
        if (ss >= 0 && ss < Sn) val = *(const ushort8_t*)(v + ((long)b*Sn + ss)*C2n + ck*8);
        *(ushort8_t*)(vs + rr*1024 + ((ck ^ (rr&7))*8)) = val;   // chunk ck stored at position ck^rsw
    }
    __syncthreads();
    int sl = threadIdx.x & 31, ob = threadIdx.x >> 5;
    for (int o = ob; o < NCONV; o += 8){
        float acc = cb[o];
        #pragma unroll
        for (int k = 0; k < 3; k++){
            int row = sl + k;
            const ushort_t* vrow = vs + row*1024;
            int rsw = row & 7;
            const float* wrow = cwT + (o*3 + k)*1024;
            float a0 = 0.f;
            for (int c8 = 0; c8 < 128; c8++){
                // position c8^rsw holds chunk c8  ->  pair with weight chunk c8 (FIX)
                ushort8_t vv = *(const ushort8_t*)(vrow + ((c8 ^ rsw)*8));
                const float* wp = wrow + c8*8;
                float4 wa = *(const float4*)(wp);
                float4 wb = *(const float4*)(wp + 4);
                a0 += bfu2f(vv[0])*wa.x + bfu2f(vv[1])*wa.y + bfu2f(vv[2])*wa.z + bfu2f(vv[3])*wa.w
                    + bfu2f(vv[4])*wb.x + bfu2f(vv[5])*wb.y + bfu2f(vv[6])*wb.z + bfu2f(vv[7])*wb.w;
            }
            acc += a0;
        }
        float rv = fmaxf(acc, 0.f);
        for (int off = 16; off > 0; off >>= 1) rv = fmaxf(rv, __shfl_down(rv, off));
        if (sl == 0) zpart[((long)b*NCONV + o)*4 + st] = rv;
    }
}

// ---------------- logits + log_softmax + NLL loss ----------------
__global__ __launch_bounds__(128) void loss_kernel(
    const float* __restrict__ zpart, const float* __restrict__ fcw,
    const float* __restrict__ fcb, const int* __restrict__ label,
    float* __restrict__ out)
{
    int b = threadIdx.x;
    float lg0 = fcb[0], lg1 = fcb[1], lg2 = fcb[2];
    for (int k = 0; k < NCONV; k++){
        const float* zp = zpart + ((long)b*NCONV + k)*4;
        float zm = fmaxf(fmaxf(zp[0], zp[1]), fmaxf(zp[2], zp[3]));
        lg0 += zm * fcw[k];
        lg1 += zm * fcw[NCONV + k];
        lg2 += zm * fcw[2*NCONV + k];
    }
    out[1 + b*3 + 0] = lg0;
    out[1 + b*3 + 1] = lg1;
    out[1 + b*3 + 2] = lg2;
    float mx = fmaxf(lg0, fmaxf(lg1, lg2));
    float sum = expf(lg0-mx) + expf(lg1-mx) + expf(lg2-mx);
    float lse = mx + logf(sum);
    int lb = label[b];
    float lp = ((lb == 0) ? lg0 : (lb == 1) ? lg1 : lg2) - lse;
    __shared__ float red[128];
    red[b] = lp; __syncthreads();
    for (int off = 64; off > 0; off >>= 1){
        if (b < off) red[b] += red[b + off];
        __syncthreads();
    }
    if (b == 0) out[0] = -red[0] / (float)Bn;
}

extern "C" void kernel_launch(void* const* d_in, const int* in_sizes, int n_in,
                              void* d_out, int out_size, void* d_ws, size_t ws_size,
                              hipStream_t stream)
{
    (void)in_sizes; (void)n_in; (void)out_size;
    if (ws_size < (size_t)WS_NEED_F * 4) return;   // clean absmax failure, not a fault
    const int* raw_text  = (const int*)d_in[0];
    const int* target    = (const int*)d_in[1];
    const int* span      = (const int*)d_in[2];
    const int* label     = (const int*)d_in[3];
    const float* embW    = (const float*)d_in[4];
    const float* l1f_Wih = (const float*)d_in[5];
    const float* l1f_Whh = (const float*)d_in[6];
    const float* l1f_b   = (const float*)d_in[7];
    const float* l1b_Wih = (const float*)d_in[8];
    const float* l1b_Whh = (const float*)d_in[9];
    const float* l1b_b   = (const float*)d_in[10];
    const float* l2f_Wih = (const float*)d_in[11];
    const float* l2f_Whh = (const float*)d_in[12];
    const float* l2f_b   = (const float*)d_in[13];
    const float* l2b_Wih = (const float*)d_in[14];
    const float* l2b_Whh = (const float*)d_in[15];
    const float* l2b_b   = (const float*)d_in[16];
    const float* conv_w  = (const float*)d_in[17];
    const float* conv_b  = (const float*)d_in[18];
    const float* fc1_w   = (const float*)d_in[19];
    const float* fc1_b   = (const float*)d_in[20];
    const float* fc_w    = (const float*)d_in[21];
    const float* fc_b    = (const float*)d_in[22];

    float* ws = (float*)d_ws;
    ushort_t* Xf1   = (ushort_t*)(ws + OFF_X1C);
    ushort_t* Xb1   = Xf1 + 4194304;
    ushort_t* Xf2   = (ushort_t*)(ws + OFF_X2);
    ushort_t* Xb2   = Xf2 + 2097152;
    ushort_t* featp = (ushort_t*)(ws + OFF_FEATP);
    ushort_t* aspp  = (ushort_t*)(ws + OFF_ASPP);
    ushort_t* WihI  = (ushort_t*)(ws + OFF_WIHI);     // 4 x 655360
    float*    biasI = ws + OFF_BIASI;                  // 4 x 2048
    ushort_t* fc1wb = (ushort_t*)(ws + OFF_FC1WB);
    float*    cwT   = ws + OFF_CWT;
    ushort_t* vbuf  = (ushort_t*)(ws + OFF_V);
    ushort_t* ebuf  = (ushort_t*)(ws + OFF_E);
    ushort_t* F2b   = (ushort_t*)(ws + OFF_F2);
    ushort_t* mo    = (ushort_t*)(ws + OFF_MO);
    float* st   = ws + OFF_STATE;
    int* lenf   = (int*)(ws + OFF_LENF);
    int* lena   = (int*)(ws + OFF_LENA);
    int* rmF1   = (int*)(ws + OFF_RMF1);
    int* rmB1   = (int*)(ws + OFF_RMB1);
    int* rm2    = (int*)(ws + OFF_RM2);
    float* wpos = ws + OFF_WPOS;
    float* zpart= ws + OFF_ZPART;

    // state: per layer {hA bf16 [2][128][512], hB same, c f32 [2][128][512]}
    ushort_t* h1A = (ushort_t*)(st);
    ushort_t* h1B = (ushort_t*)(st + 65536);
    float*    c1  = st + 131072;
    float* st2 = st + 262144;
    ushort_t* h2A = (ushort_t*)(st2);
    ushort_t* h2B = (ushort_t*)(st2 + 65536);
    float*    c2  = st2 + 131072;

    zero_kernel<<<2048, 256, 0, stream>>>(st, 524288L);
    prep_kernel<<<Bn, 128, 0, stream>>>(raw_text, target, span, lenf, lena, rmF1, rmB1, rm2, wpos);
    embed_kernel<<<(Bn*Sn*EnP + 255)/256, 256, 0, stream>>>(raw_text, embW, featp, (long)Bn*Sn);
    embed_kernel<<<(Bn*Tn*EnP + 255)/256, 256, 0, stream>>>(target, embW, aspp, (long)Bn*Tn);

    // weight conversions (gate-interleaved Wih + bias; plain fc1; conv transpose)
    const float* wih_src[4]  = {l1f_Wih, l1b_Wih, l2f_Wih, l2b_Wih};
    const float* bias_src[4] = {l1f_b,   l1b_b,   l2f_b,   l2b_b};
    for (int d = 0; d < 4; d++){
        cvtpad_inter<<<(Gn*EnP + 255)/256, 256, 0, stream>>>(wih_src[d], WihI + (long)d*655360);
        bias_inter<<<8, 256, 0, stream>>>(bias_src[d], biasI + d*2048);
    }
    cvtpad_kernel<<<(1024*2048 + 255)/256, 256, 0, stream>>>(fc1_w, fc1wb, 1024, 2048, 2048);
    convw_kernel<<<(NCONV*3072 + 255)/256, 256, 0, stream>>>(conv_w, cwT);

    // layer-1 biLSTM: chunked MFMA input projection + MFMA steps
    dim3 gc(Gn/128, (Bn*CH)/128);   // (16, 16)
    dim3 gl(32, 2);
    for (int c = 0; c < NCH; c++){
        mfma_gemm<<<gc, 256, 0, stream>>>(featp, EnP, rmF1 + c*Bn*CH, WihI,            EnP, biasI,        Xf1, Gn, Bn*CH, Gn, EnP);
        mfma_gemm<<<gc, 256, 0, stream>>>(featp, EnP, rmB1 + c*Bn*CH, WihI + 655360,   EnP, biasI + 2048, Xb1, Gn, Bn*CH, Gn, EnP);
        for (int tt = 0; tt < CH; tt++){
            int t = c*CH + tt;
            const ushort_t* hpv = (t & 1) ? h1B : h1A;
            ushort_t*       hnv = (t & 1) ? h1A : h1B;
            lstm_step2<<<gl, 256, 0, stream>>>(l1f_Whh, l1b_Whh, Xf1, Xb1,
                hpv, hnv, c1, vbuf, lenf, t, tt, Sn, CH);
        }
    }
    // layer-2 biLSTM
    dim3 g2(Gn/128, (Bn*Tn)/128);   // (16, 8)
    mfma_gemm<<<g2, 256, 0, stream>>>(aspp, EnP, nullptr, WihI + 2L*655360, EnP, biasI + 4096, Xf2, Gn, Bn*Tn, Gn, EnP);
    mfma_gemm<<<g2, 256, 0, stream>>>(aspp, EnP, rm2,     WihI + 3L*655360, EnP, biasI + 6144, Xb2, Gn, Bn*Tn, Gn, EnP);
    for (int t = 0; t < Tn; t++){
        const ushort_t* hpv = (t & 1) ? h2B : h2A;
        ushort_t*       hnv = (t & 1) ? h2A : h2B;
        lstm_step2<<<gl, 256, 0, stream>>>(l2f_Whh, l2b_Whh, Xf2, Xb2,
            hpv, hnv, c2, ebuf, lena, t, t, Tn, Tn);
    }

    // F2 = e @ W1^T  (fc1_w cols 0..1023)
    dim3 gF(C2n/128, (Bn*Tn)/128);  // (8, 8)
    mfma_gemm<<<gF, 256, 0, stream>>>(ebuf, C2n, nullptr, fc1wb, 2048, nullptr, F2b, C2n, Bn*Tn, C2n, C2n);

    // 2 CPT iterations: mo = v @ W2^T, then fused attention/fc1/residual
    dim3 gm(C2n/128, (Bn*Sn)/128);  // (8, 128)
    for (int it = 0; it < 2; it++){
        mfma_gemm<<<gm, 256, 0, stream>>>(vbuf, C2n, nullptr, fc1wb + 1024, 2048, nullptr, mo, C2n, Bn*Sn, C2n, C2n);
        attn2_kernel<<<dim3(Sn, Bn), 256, 0, stream>>>(vbuf, ebuf, F2b, mo, fc1_b, wpos);
    }

    conv2_kernel<<<dim3(4, Bn), 256, 0, stream>>>(vbuf, cwT, conv_b, zpart);
    loss_kernel<<<1, 128, 0, stream>>>(zpart, fc_w, fc_b, label, (float*)d_out);
}